// Round 12
// baseline (105.353 us; speedup 1.0000x reference)
//
#include <hip/hip_runtime.h>

#define ND 256       // embedding dim
#define NK 512       // centroids
#define LM2 0.0625f  // lambda^2
#define DELTA 0.25f  // approx top-2 gap below this -> exact fp32 rescore

typedef _Float16 f16x8 __attribute__((ext_vector_type(8)));
typedef float f32x4 __attribute__((ext_vector_type(4)));
typedef unsigned short u16x8 __attribute__((ext_vector_type(8)));
typedef unsigned short u16x4 __attribute__((ext_vector_type(4)));

// async 16B global->LDS (zero VGPR staging). LDS dest is wave-uniform base
// (HW adds lane*16); global src is per-lane.
#define GLD16(GSRC, LDST)                                                      \
    __builtin_amdgcn_global_load_lds(                                         \
        (const __attribute__((address_space(1))) void*)(GSRC),                \
        (__attribute__((address_space(3))) void*)(LDST), 16, 0, 0)

// ---------------- prep: csq[k] + fp16 centroids in per-64col-panel frag order --
// Cf layout: [panel 8][krow 32][col 64][8], krow = (d>>5)*4 + ((d>>3)&3).
// 16B granule = one lane's B-frag slice (measured 0 bank conflicts r4-r11).
__global__ __launch_bounds__(64) void prep_kernel(const float* __restrict__ Cg,
                                                  float* __restrict__ csq,
                                                  unsigned short* __restrict__ Cf) {
    const int k = blockIdx.x, lane = threadIdx.x;
    float4 v = *(const float4*)(Cg + (size_t)k * ND + lane * 4);
    float s = v.x * v.x + v.y * v.y + v.z * v.z + v.w * v.w;
#pragma unroll
    for (int m = 1; m <= 32; m <<= 1) s += __shfl_xor(s, m, 64);
    if (lane == 0) csq[k] = s;
    u16x4 h;
    h[0] = __builtin_bit_cast(unsigned short, (_Float16)v.x);
    h[1] = __builtin_bit_cast(unsigned short, (_Float16)v.y);
    h[2] = __builtin_bit_cast(unsigned short, (_Float16)v.z);
    h[3] = __builtin_bit_cast(unsigned short, (_Float16)v.w);
    const int panel = k >> 6, col = k & 63;
    const int krow = (lane >> 3) * 4 + ((lane >> 1) & 3);  // d0 = lane*4
    const size_t idx = ((size_t)panel << 14) + ((((size_t)krow << 6) + col) << 3) + ((lane & 1) << 2);
    *(u16x4*)(Cf + idx) = h;
}

// ---------------- main: 4 waves x 32 rows; A staged fp32 via gload_lds -------
// grid 1024 x 256 thr. A-stage: fp32 rowtile lands in the 64KB B-buffer space
// via global_load_lds (zero staging regs -> no spill, full-MLP burst), waves
// convert LDS->A[2][8] fp16 regs (transient = 8 regs). Then r10's panel loop:
// B panels (64 cols, 32 KB) double-buffered via gload_lds, ONE barrier/panel,
// running per-lane u32 top-2 keys, single merge at end.
// A-pad granule layout per wave segment (16 KB/phase): [ks2 4][l4 4][half 2][row 32],
// granule=16B -> gload fill is linear, cvt reads are 16B-contiguous per lane.
__global__ __launch_bounds__(256, 2) void kmeans_mfma(
    const float* __restrict__ E, const unsigned short* __restrict__ Cf,
    const float* __restrict__ csq, uint2* __restrict__ partials,
    float* __restrict__ e2s) {
    __shared__ unsigned short Bbuf[2][16384];  // 2 x 32 KB (also A landing pad)

    const int tid = threadIdx.x;
    const int lane = tid & 63, wid = tid >> 6;  // wid 0..3
    const int l15 = lane & 15, l4 = lane >> 4;
    const int rowbase = blockIdx.x << 7;
    const int wrow = rowbase + wid * 32;

    unsigned short* Apad = &Bbuf[0][0];  // 64 KB flat; wave seg = 8192 shorts

    f16x8 A[2][8];  // [m][ks] fp16, 64 VGPR
    float e2 = 0.f;

#pragma unroll
    for (int ph = 0; ph < 2; ++ph) {
        // ---- issue 16 KB/wave of fp32 A into LDS (16 slots, zero regs) ----
#pragma unroll
        for (int s = 0; s < 16; ++s) {
            const int g = s * 64 + lane;  // granule in wave segment
            const int row = g & 31, half = (g >> 5) & 1, l4g = (g >> 6) & 3, ks2 = g >> 8;
            const float* src = E + (size_t)(wrow + row) * ND + (ph * 4 + ks2) * 32 + l4g * 8 + half * 4;
            GLD16(src, &Apad[(size_t)(wid * 16 + s) << 9]);
        }
        __syncthreads();  // drains vmcnt: phase data staged
        // ---- convert own rows LDS -> A regs (+ e2, exact fp32) ----
#pragma unroll
        for (int ks2 = 0; ks2 < 4; ++ks2) {
#pragma unroll
            for (int m = 0; m < 2; ++m) {
                const int so = wid * 8192 + (ks2 * 8 + l4 * 2) * 256 + (l15 + 16 * m) * 8;
                const float4 v0 = *(const float4*)&Apad[so];        // k 0-3 (half 0)
                const float4 v1 = *(const float4*)&Apad[so + 256];  // k 4-7 (half 1)
                e2 += v0.x * v0.x + v0.y * v0.y + v0.z * v0.z + v0.w * v0.w +
                      v1.x * v1.x + v1.y * v1.y + v1.z * v1.z + v1.w * v1.w;
                u16x8 h;
                h[0] = __builtin_bit_cast(unsigned short, (_Float16)v0.x);
                h[1] = __builtin_bit_cast(unsigned short, (_Float16)v0.y);
                h[2] = __builtin_bit_cast(unsigned short, (_Float16)v0.z);
                h[3] = __builtin_bit_cast(unsigned short, (_Float16)v0.w);
                h[4] = __builtin_bit_cast(unsigned short, (_Float16)v1.x);
                h[5] = __builtin_bit_cast(unsigned short, (_Float16)v1.y);
                h[6] = __builtin_bit_cast(unsigned short, (_Float16)v1.z);
                h[7] = __builtin_bit_cast(unsigned short, (_Float16)v1.w);
                A[m][ph * 4 + ks2] = __builtin_bit_cast(f16x8, h);
            }
        }
        __syncthreads();  // cvt reads done before pad is overwritten
    }

    // ---- stage B panel 0 (Bbuf[0] now free) ----
#pragma unroll
    for (int i = 0; i < 8; ++i)
        GLD16(Cf + (((size_t)(wid * 8 + i) * 64 + lane) << 3),
              &Bbuf[0][(size_t)(wid * 8 + i) << 9]);

    unsigned k1[2][4], k2[2][4];
#pragma unroll
    for (int m = 0; m < 2; ++m)
#pragma unroll
        for (int j = 0; j < 4; ++j) { k1[m][j] = 0u; k2[m][j] = 0u; }

#pragma unroll 1
    for (int p = 0; p < 8; ++p) {
        __syncthreads();  // drains vmcnt: panel p staged; buf[(p+1)&1] free
        if (p < 7) {      // issue next panel (lands during this panel's compute)
            const unsigned short* gsrc = Cf + ((size_t)(p + 1) << 14);
            unsigned short* ldst = (unsigned short*)Bbuf[(p + 1) & 1];
#pragma unroll
            for (int i = 0; i < 8; ++i)
                GLD16(gsrc + (((size_t)(wid * 8 + i) * 64 + lane) << 3),
                      &ldst[(size_t)(wid * 8 + i) << 9]);
        }
        float csp[4];
        unsigned ck[4];
#pragma unroll
        for (int n = 0; n < 4; ++n) {
            const int col = (p << 6) + n * 16 + l15;
            csp[n] = csq[col];
            ck[n] = (unsigned)(NK - 1 - col);
        }
        // compute current panel: 8 ks x {4 B-frag ds_read_b128, 8 MFMA}
        const unsigned short* cur = Bbuf[p & 1];
        f32x4 acc[2][4] = {};
#pragma unroll
        for (int ks = 0; ks < 8; ++ks) {
            u16x8 bf[4];
#pragma unroll
            for (int n = 0; n < 4; ++n)
                bf[n] = *(const u16x8*)&cur[(size_t)((((ks << 2) + l4) << 6) + n * 16 + l15) << 3];
#pragma unroll
            for (int m = 0; m < 2; ++m)
#pragma unroll
                for (int n = 0; n < 4; ++n)
                    acc[m][n] = __builtin_amdgcn_mfma_f32_16x16x32_f16(
                        A[m][ks], __builtin_bit_cast(f16x8, bf[n]), acc[m][n], 0, 0, 0);
        }
        // fold panel into running per-lane u32 top-2 keys
        // key = mono(score) with low 9 bits = 511-col (chop err ~5e-3 << DELTA)
#pragma unroll
        for (int m = 0; m < 2; ++m)
#pragma unroll
            for (int j = 0; j < 4; ++j)
#pragma unroll
                for (int n = 0; n < 4; ++n) {
                    const float s = fmaf(-2.f, acc[m][n][j], csp[n]);
                    const unsigned b = __builtin_bit_cast(unsigned, s);
                    const unsigned mono = b ^ ((unsigned)((int)b >> 31) | 0x80000000u);
                    const unsigned key = (mono & 0xFFFFFE00u) | ck[n];
                    const unsigned mn = min(k1[m][j], key);
                    k1[m][j] = max(k1[m][j], key);
                    k2[m][j] = max(k2[m][j], mn);
                }
    }

    // ---- single end-of-block merge across the 16 l15 lanes ----
#pragma unroll
    for (int m = 0; m < 2; ++m)
#pragma unroll
        for (int j = 0; j < 4; ++j) {
            unsigned a = k1[m][j], b2 = k2[m][j];
#pragma unroll
            for (int mk = 1; mk <= 8; mk <<= 1) {
                const unsigned oa = __shfl_xor(a, mk, 64);
                const unsigned ob = __shfl_xor(b2, mk, 64);
                const unsigned mn = min(a, oa);
                a = max(a, oa);
                b2 = max(max(b2, ob), mn);
            }
            if (l15 == 0) {
                const int row = wrow + m * 16 + l4 * 4 + j;
                uint2 o;
                o.x = a;
                o.y = b2;
                partials[row] = o;
            }
        }

    // ---- e2 partial (each row counted exactly once chip-wide) ----
#pragma unroll
    for (int mk = 1; mk <= 32; mk <<= 1) e2 += __shfl_xor(e2, mk, 64);
    if (lane == 0) e2s[blockIdx.x * 4 + wid] = e2;
}

// ---------------- combine: decode top-2 keys, rescore near-ties --------------
__global__ __launch_bounds__(256) void combine_kernel(
    const uint2* __restrict__ partials, const float* __restrict__ csq,
    const float* __restrict__ E, const float* __restrict__ Cg,
    float* __restrict__ out, float* __restrict__ sum2) {
    const int n = blockIdx.x * 256 + threadIdx.x;
    const uint2 kk = partials[n];
    const unsigned m1 = kk.x & 0xFFFFFE00u;
    float v1 = __builtin_bit_cast(float, (m1 & 0x80000000u) ? (m1 ^ 0x80000000u) : ~m1);
    int i1 = (int)(NK - 1) - (int)(kk.x & 511u);
    const unsigned m2 = kk.y & 0xFFFFFE00u;
    const float v2 = __builtin_bit_cast(float, (m2 & 0x80000000u) ? (m2 ^ 0x80000000u) : ~m2);
    const int i2 = (int)(NK - 1) - (int)(kk.y & 511u);

    if (v1 - v2 <= DELTA) {  // near-tie: exact fp32 rescore of both candidates
        const float* e = E + (size_t)n * ND;
        const float* c1p = Cg + (size_t)i1 * ND;
        const float* c2p = Cg + (size_t)i2 * ND;
        float d1 = 0.f, d2 = 0.f;
        for (int d = 0; d < ND; d += 4) {
            float4 ev = *(const float4*)(e + d);
            float4 cv1 = *(const float4*)(c1p + d);
            float4 cv2 = *(const float4*)(c2p + d);
            d1 += ev.x * cv1.x + ev.y * cv1.y + ev.z * cv1.z + ev.w * cv1.w;
            d2 += ev.x * cv2.x + ev.y * cv2.y + ev.z * cv2.z + ev.w * cv2.w;
        }
        const float s1 = csq[i1] - 2.f * d1;
        const float s2 = csq[i2] - 2.f * d2;
        if (s2 > s1 || (s2 == s1 && i2 < i1)) { v1 = s2; i1 = i2; } else { v1 = s1; }
    }
    out[1 + n] = (float)i1;
    float s = v1;
#pragma unroll
    for (int mk = 1; mk <= 32; mk <<= 1) s += __shfl_xor(s, mk, 64);
    __shared__ float wsm[4];
    const int lane = threadIdx.x & 63, wd = threadIdx.x >> 6;
    if (lane == 0) wsm[wd] = s;
    __syncthreads();
    if (threadIdx.x == 0) sum2[blockIdx.x] = wsm[0] + wsm[1] + wsm[2] + wsm[3];
}

// ---------------- final: loss = lambda^2 * (sum e^2 + sum row maxima) --------
__global__ __launch_bounds__(256) void final_kernel(const float* __restrict__ e2s,
                                                    const float* __restrict__ sum2,
                                                    float* __restrict__ out) {
    float s = 0.f;
    for (int i = threadIdx.x; i < 4096; i += 256) s += e2s[i];
    for (int i = threadIdx.x; i < 512; i += 256) s += sum2[i];
#pragma unroll
    for (int mk = 1; mk <= 32; mk <<= 1) s += __shfl_xor(s, mk, 64);
    __shared__ float wsm[4];
    const int lane = threadIdx.x & 63, wd = threadIdx.x >> 6;
    if (lane == 0) wsm[wd] = s;
    __syncthreads();
    if (threadIdx.x == 0) out[0] = LM2 * (wsm[0] + wsm[1] + wsm[2] + wsm[3]);
}

extern "C" void kernel_launch(void* const* d_in, const int* in_sizes, int n_in,
                              void* d_out, int out_size, void* d_ws, size_t ws_size,
                              hipStream_t stream) {
    (void)n_in; (void)out_size; (void)ws_size;
    const float* E = (const float*)d_in[0];
    const float* Cg = (const float*)d_in[1];
    float* out = (float*)d_out;

    // ws (floats): csq[512] | e2s[4096] | sum2[512] | Cf16 (256KB) | partials (1MB)
    float* wsf = (float*)d_ws;
    float* csq = wsf;
    float* e2s = wsf + 512;
    float* sum2 = wsf + 4608;
    unsigned short* Cf = (unsigned short*)(wsf + 5120);
    uint2* partials = (uint2*)(wsf + 5120 + 65536);

    const int N = in_sizes[0] / ND;  // 131072
    const int nblk = N >> 7;         // 1024

    prep_kernel<<<NK, 64, 0, stream>>>(Cg, csq, Cf);
    kmeans_mfma<<<nblk, 256, 0, stream>>>(E, Cf, csq, partials, e2s);
    combine_kernel<<<N / 256, 256, 0, stream>>>(partials, csq, E, Cg, out, sum2);
    final_kernel<<<1, 256, 0, stream>>>(e2s, sum2, out);
}

// Round 13
// 102.477 us; speedup vs baseline: 1.0281x; 1.0281x over previous
//
#include <hip/hip_runtime.h>

#define ND 256       // embedding dim
#define NK 512       // centroids
#define LM2 0.0625f  // lambda^2
#define DELTA 0.25f  // approx top-2 gap below this -> exact fp32 rescore

typedef _Float16 f16x8 __attribute__((ext_vector_type(8)));
typedef float f32x4 __attribute__((ext_vector_type(4)));
typedef unsigned short u16x8 __attribute__((ext_vector_type(8)));
typedef unsigned short u16x4 __attribute__((ext_vector_type(4)));

// async 16B global->LDS (zero VGPR staging). LDS dest is wave-uniform base
// (HW adds lane*16); global src is per-lane.
#define GLD16(GSRC, LDST)                                                      \
    __builtin_amdgcn_global_load_lds(                                         \
        (const __attribute__((address_space(1))) void*)(GSRC),                \
        (__attribute__((address_space(3))) void*)(LDST), 16, 0, 0)

// ---------------- prep: csq[k] + fp16 centroids in per-64col-panel frag order --
// Cf layout: [panel 8][krow 32][col 64][8], krow = (d>>5)*4 + ((d>>3)&3).
// 16B granule = one lane's B-frag slice (measured 0 bank conflicts r4-r12).
__global__ __launch_bounds__(64) void prep_kernel(const float* __restrict__ Cg,
                                                  float* __restrict__ csq,
                                                  unsigned short* __restrict__ Cf) {
    const int k = blockIdx.x, lane = threadIdx.x;
    float4 v = *(const float4*)(Cg + (size_t)k * ND + lane * 4);
    float s = v.x * v.x + v.y * v.y + v.z * v.z + v.w * v.w;
#pragma unroll
    for (int m = 1; m <= 32; m <<= 1) s += __shfl_xor(s, m, 64);
    if (lane == 0) csq[k] = s;
    u16x4 h;
    h[0] = __builtin_bit_cast(unsigned short, (_Float16)v.x);
    h[1] = __builtin_bit_cast(unsigned short, (_Float16)v.y);
    h[2] = __builtin_bit_cast(unsigned short, (_Float16)v.z);
    h[3] = __builtin_bit_cast(unsigned short, (_Float16)v.w);
    const int panel = k >> 6, col = k & 63;
    const int krow = (lane >> 3) * 4 + ((lane >> 1) & 3);  // d0 = lane*4
    const size_t idx = ((size_t)panel << 14) + ((((size_t)krow << 6) + col) << 3) + ((lane & 1) << 2);
    *(u16x4*)(Cf + idx) = h;
}

// ---------------- main: 8 waves x 16 rows, LOW ARCH PRESSURE (~85 regs) ------
// grid 1024 x 512 thr: 128 rows/block. A[8]=32 VGPR per thread (16 rows/wave)
// -> panel-loop arch liveness ~85 << 128 cap: no spill even under the
// accum_offset=128 split that bit r9-r12 at 32 rows/wave. launch_bounds(512,2)
// (r11's (512,4) capped VGPR at 64 -> that was its spill). B panels (64 cols,
// 32 KB) double-buffered via gload_lds, ONE barrier/panel. u32 top-2 keys.
__global__ __launch_bounds__(512, 2) void kmeans_mfma(
    const float* __restrict__ E, const unsigned short* __restrict__ Cf,
    const float* __restrict__ csq, uint2* __restrict__ partials,
    float* __restrict__ e2s) {
    __shared__ unsigned short Bbuf[2][16384];  // 2 x 32 KB

    const int tid = threadIdx.x;
    const int lane = tid & 63, wid = tid >> 6;  // wid 0..7
    const int l15 = lane & 15, l4 = lane >> 4;
    const int rowbase = blockIdx.x << 7;
    const int wrow = rowbase + wid * 16;

    // ---- issue panel 0 staging (flies during A-stage); 4 slots per wave ----
#pragma unroll
    for (int i = 0; i < 4; ++i)
        GLD16(Cf + (((size_t)(wid * 4 + i) * 64 + lane) << 3),
              &Bbuf[0][(size_t)(wid * 4 + i) << 9]);

    // ---- A stage: one row per l15 lane, 2 chunks of 4 ks (t[8]=32 transient) --
    const float* ap = E + (size_t)(wrow + l15) * ND + l4 * 8;

    f16x8 A[8];  // [ks], 32 VGPR
    float e2 = 0.f;
#pragma unroll
    for (int half = 0; half < 2; ++half) {
        float4 t[8];
#pragma unroll
        for (int q = 0; q < 4; ++q) {
            t[q * 2]     = *(const float4*)(ap + (half * 4 + q) * 32);
            t[q * 2 + 1] = *(const float4*)(ap + (half * 4 + q) * 32 + 4);
        }
#pragma unroll
        for (int q = 0; q < 4; ++q) {
            float4 v0 = t[q * 2], v1 = t[q * 2 + 1];
            e2 += v0.x * v0.x + v0.y * v0.y + v0.z * v0.z + v0.w * v0.w +
                  v1.x * v1.x + v1.y * v1.y + v1.z * v1.z + v1.w * v1.w;
            u16x8 h;
            h[0] = __builtin_bit_cast(unsigned short, (_Float16)v0.x);
            h[1] = __builtin_bit_cast(unsigned short, (_Float16)v0.y);
            h[2] = __builtin_bit_cast(unsigned short, (_Float16)v0.z);
            h[3] = __builtin_bit_cast(unsigned short, (_Float16)v0.w);
            h[4] = __builtin_bit_cast(unsigned short, (_Float16)v1.x);
            h[5] = __builtin_bit_cast(unsigned short, (_Float16)v1.y);
            h[6] = __builtin_bit_cast(unsigned short, (_Float16)v1.z);
            h[7] = __builtin_bit_cast(unsigned short, (_Float16)v1.w);
            A[half * 4 + q] = __builtin_bit_cast(f16x8, h);
        }
    }

    unsigned k1[4], k2[4];
#pragma unroll
    for (int j = 0; j < 4; ++j) { k1[j] = 0u; k2[j] = 0u; }

#pragma unroll 1
    for (int p = 0; p < 8; ++p) {
        __syncthreads();  // per-wave vmcnt drain + barrier: panel p staged
        if (p < 7) {      // issue next panel (lands during this panel's compute)
            const unsigned short* gsrc = Cf + ((size_t)(p + 1) << 14);
            unsigned short* ldst = (unsigned short*)Bbuf[(p + 1) & 1];
#pragma unroll
            for (int i = 0; i < 4; ++i)
                GLD16(gsrc + (((size_t)(wid * 4 + i) * 64 + lane) << 3),
                      &ldst[(size_t)(wid * 4 + i) << 9]);
        }
        float csp[4];
        unsigned ck[4];
#pragma unroll
        for (int n = 0; n < 4; ++n) {
            const int col = (p << 6) + n * 16 + l15;
            csp[n] = csq[col];
            ck[n] = (unsigned)(NK - 1 - col);
        }
        // compute current panel: 8 ks x {4 B-frag ds_read_b128, 4 MFMA}
        const unsigned short* cur = Bbuf[p & 1];
        f32x4 acc[4] = {};
#pragma unroll
        for (int ks = 0; ks < 8; ++ks) {
            u16x8 bf[4];
#pragma unroll
            for (int n = 0; n < 4; ++n)
                bf[n] = *(const u16x8*)&cur[(size_t)((((ks << 2) + l4) << 6) + n * 16 + l15) << 3];
#pragma unroll
            for (int n = 0; n < 4; ++n)
                acc[n] = __builtin_amdgcn_mfma_f32_16x16x32_f16(
                    A[ks], __builtin_bit_cast(f16x8, bf[n]), acc[n], 0, 0, 0);
        }
        // fold panel into running per-lane u32 top-2 keys
        // key = mono(score) with low 9 bits = 511-col (chop err ~5e-3 << DELTA)
#pragma unroll
        for (int j = 0; j < 4; ++j)
#pragma unroll
            for (int n = 0; n < 4; ++n) {
                const float s = fmaf(-2.f, acc[n][j], csp[n]);
                const unsigned b = __builtin_bit_cast(unsigned, s);
                const unsigned mono = b ^ ((unsigned)((int)b >> 31) | 0x80000000u);
                const unsigned key = (mono & 0xFFFFFE00u) | ck[n];
                const unsigned mn = min(k1[j], key);
                k1[j] = max(k1[j], key);
                k2[j] = max(k2[j], mn);
            }
    }

    // ---- single end-of-block merge across the 16 l15 lanes ----
#pragma unroll
    for (int j = 0; j < 4; ++j) {
        unsigned a = k1[j], b2 = k2[j];
#pragma unroll
        for (int mk = 1; mk <= 8; mk <<= 1) {
            const unsigned oa = __shfl_xor(a, mk, 64);
            const unsigned ob = __shfl_xor(b2, mk, 64);
            const unsigned mn = min(a, oa);
            a = max(a, oa);
            b2 = max(max(b2, ob), mn);
        }
        if (l15 == 0) {
            const int row = wrow + l4 * 4 + j;
            uint2 o;
            o.x = a;
            o.y = b2;
            partials[row] = o;
        }
    }

    // ---- e2 partial (each row counted exactly once chip-wide) ----
#pragma unroll
    for (int mk = 1; mk <= 32; mk <<= 1) e2 += __shfl_xor(e2, mk, 64);
    if (lane == 0) e2s[blockIdx.x * 8 + wid] = e2;
}

// ---------------- combine: decode top-2 keys, rescore near-ties --------------
__global__ __launch_bounds__(256) void combine_kernel(
    const uint2* __restrict__ partials, const float* __restrict__ csq,
    const float* __restrict__ E, const float* __restrict__ Cg,
    float* __restrict__ out, float* __restrict__ sum2) {
    const int n = blockIdx.x * 256 + threadIdx.x;
    const uint2 kk = partials[n];
    const unsigned m1 = kk.x & 0xFFFFFE00u;
    float v1 = __builtin_bit_cast(float, (m1 & 0x80000000u) ? (m1 ^ 0x80000000u) : ~m1);
    int i1 = (int)(NK - 1) - (int)(kk.x & 511u);
    const unsigned m2 = kk.y & 0xFFFFFE00u;
    const float v2 = __builtin_bit_cast(float, (m2 & 0x80000000u) ? (m2 ^ 0x80000000u) : ~m2);
    const int i2 = (int)(NK - 1) - (int)(kk.y & 511u);

    if (v1 - v2 <= DELTA) {  // near-tie: exact fp32 rescore of both candidates
        const float* e = E + (size_t)n * ND;
        const float* c1p = Cg + (size_t)i1 * ND;
        const float* c2p = Cg + (size_t)i2 * ND;
        float d1 = 0.f, d2 = 0.f;
        for (int d = 0; d < ND; d += 4) {
            float4 ev = *(const float4*)(e + d);
            float4 cv1 = *(const float4*)(c1p + d);
            float4 cv2 = *(const float4*)(c2p + d);
            d1 += ev.x * cv1.x + ev.y * cv1.y + ev.z * cv1.z + ev.w * cv1.w;
            d2 += ev.x * cv2.x + ev.y * cv2.y + ev.z * cv2.z + ev.w * cv2.w;
        }
        const float s1 = csq[i1] - 2.f * d1;
        const float s2 = csq[i2] - 2.f * d2;
        if (s2 > s1 || (s2 == s1 && i2 < i1)) { v1 = s2; i1 = i2; } else { v1 = s1; }
    }
    out[1 + n] = (float)i1;
    float s = v1;
#pragma unroll
    for (int mk = 1; mk <= 32; mk <<= 1) s += __shfl_xor(s, mk, 64);
    __shared__ float wsm[4];
    const int lane = threadIdx.x & 63, wd = threadIdx.x >> 6;
    if (lane == 0) wsm[wd] = s;
    __syncthreads();
    if (threadIdx.x == 0) sum2[blockIdx.x] = wsm[0] + wsm[1] + wsm[2] + wsm[3];
}

// ---------------- final: loss = lambda^2 * (sum e^2 + sum row maxima) --------
__global__ __launch_bounds__(256) void final_kernel(const float* __restrict__ e2s,
                                                    const float* __restrict__ sum2,
                                                    float* __restrict__ out) {
    float s = 0.f;
    for (int i = threadIdx.x; i < 8192; i += 256) s += e2s[i];
    for (int i = threadIdx.x; i < 512; i += 256) s += sum2[i];
#pragma unroll
    for (int mk = 1; mk <= 32; mk <<= 1) s += __shfl_xor(s, mk, 64);
    __shared__ float wsm[4];
    const int lane = threadIdx.x & 63, wd = threadIdx.x >> 6;
    if (lane == 0) wsm[wd] = s;
    __syncthreads();
    if (threadIdx.x == 0) out[0] = LM2 * (wsm[0] + wsm[1] + wsm[2] + wsm[3]);
}

extern "C" void kernel_launch(void* const* d_in, const int* in_sizes, int n_in,
                              void* d_out, int out_size, void* d_ws, size_t ws_size,
                              hipStream_t stream) {
    (void)n_in; (void)out_size; (void)ws_size;
    const float* E = (const float*)d_in[0];
    const float* Cg = (const float*)d_in[1];
    float* out = (float*)d_out;

    // ws (floats): csq[512] | e2s[8192] | sum2[512] | Cf16 (256KB) | partials (1MB)
    float* wsf = (float*)d_ws;
    float* csq = wsf;
    float* e2s = wsf + 512;
    float* sum2 = wsf + 8704;
    unsigned short* Cf = (unsigned short*)(wsf + 9216);
    uint2* partials = (uint2*)(wsf + 9216 + 65536);

    const int N = in_sizes[0] / ND;  // 131072
    const int nblk = N >> 7;         // 1024

    prep_kernel<<<NK, 64, 0, stream>>>(Cg, csq, Cf);
    kmeans_mfma<<<nblk, 512, 0, stream>>>(E, Cf, csq, partials, e2s);
    combine_kernel<<<N / 256, 256, 0, stream>>>(partials, csq, E, Cg, out, sum2);
    final_kernel<<<1, 256, 0, stream>>>(e2s, sum2, out);
}